// Round 6
// baseline (43.521 us; speedup 1.0000x reference)
//
#include <hip/hip_runtime.h>

#define Bn 128
#define Qn 32
#define Dn 512
#define En 300
#define Kn 21
#define NC 16            // doc chunks of 32 per batch
#define NTHR 256

typedef __attribute__((ext_vector_type(8))) short bf16x8;
typedef __attribute__((ext_vector_type(4))) float f32x4;

__device__ __forceinline__ float dot4(float4 a, float4 b) {
    return a.x * b.x + a.y * b.y + a.z * b.z + a.w * b.w;
}

// 8 scaled floats -> bf16x8 (round-half-up, validated in R4/R5)
__device__ __forceinline__ bf16x8 pack8(float4 lo, float4 hi, float s) {
    uint4 u;
    u.x = __builtin_amdgcn_perm(__float_as_uint(lo.y * s) + 0x8000u,
                                __float_as_uint(lo.x * s) + 0x8000u, 0x07060302u);
    u.y = __builtin_amdgcn_perm(__float_as_uint(lo.w * s) + 0x8000u,
                                __float_as_uint(lo.z * s) + 0x8000u, 0x07060302u);
    u.z = __builtin_amdgcn_perm(__float_as_uint(hi.y * s) + 0x8000u,
                                __float_as_uint(hi.x * s) + 0x8000u, 0x07060302u);
    u.w = __builtin_amdgcn_perm(__float_as_uint(hi.w * s) + 0x8000u,
                                __float_as_uint(hi.z * s) + 0x8000u, 0x07060302u);
    union { uint4 u4; bf16x8 v; } cv; cv.u4 = u;
    return cv.v;
}

// wave-local LDS fence: drain DS ops, block compiler reordering (rule 18 guard)
#define WAVE_FENCE() do {                                   \
    asm volatile("s_waitcnt lgkmcnt(0)" ::: "memory");      \
    __builtin_amdgcn_wave_barrier();                        \
    __builtin_amdgcn_sched_barrier(0);                      \
} while (0)

__global__ __launch_bounds__(NTHR, 2)
void knrm_main(const int* __restrict__ qidx, const int* __restrict__ didx,
               const int* __restrict__ dlen_arr, const float* __restrict__ table,
               float* __restrict__ partial)
{
    // XCD-contiguous remap (bijective, 2048 % 8 == 0): same-batch chunk blocks
    // land on one XCD -> q rows reused in that XCD's L2.
    const int g = blockIdx.x;
    const int idx2 = (g & 7) * 256 + (g >> 3);
    const int b = idx2 >> 4;
    const int c = idx2 & 15;
    const int dlen = dlen_arr[b];
    if (c * 32 >= dlen) return;      // inactive chunk: reduce kernel skips it

    __shared__ float red[4][4][16][Kn];   // [wave][koct][frow][k] = 21504 B

    const int t = threadIdx.x;
    const int lane = t & 63;
    const int w = t >> 6;            // wave 0..3
    const int qt = w >> 1;           // q-tile (16 rows)
    const int dt = w & 1;            // d-tile (16 docs)
    const int frow = lane & 15;
    const int koct = lane >> 4;

    const int doc = c * 32 + dt * 16 + frow;
    const bool dvalid = (doc < dlen);
    const int qtok = qidx[b * Qn + qt * 16 + frow];
    const int dtok = didx[b * Dn + (dvalid ? doc : 0)];
    const float* qrow = table + (size_t)qtok * En;
    const float* drow = table + (size_t)dtok * En;

    // ---- gather fragments straight into registers (40 independent loads).
    //      lane (frow,koct) needs floats [kt*32+koct*8, +8); zero-pad past 300.
    float4 va[20], vb[20];
    const float4 z4 = make_float4(0.f, 0.f, 0.f, 0.f);
    #pragma unroll
    for (int kt = 0; kt < 10; ++kt) {
        const int k0 = kt * 32 + koct * 8;
        va[2 * kt]     = (k0 <= 296) ? *(const float4*)(qrow + k0)     : z4;
        va[2 * kt + 1] = (k0 <= 288) ? *(const float4*)(qrow + k0 + 4) : z4;
        vb[2 * kt]     = (k0 <= 296) ? *(const float4*)(drow + k0)     : z4;
        vb[2 * kt + 1] = (k0 <= 288) ? *(const float4*)(drow + k0 + 4) : z4;
    }

    // ---- row norms: each row's 320 floats live in the 4 koct-lanes of frow
    float sa = 0.f, sb = 0.f;
    #pragma unroll
    for (int i = 0; i < 20; ++i) { sa += dot4(va[i], va[i]); sb += dot4(vb[i], vb[i]); }
    sa += __shfl_xor(sa, 16); sa += __shfl_xor(sa, 32);
    sb += __shfl_xor(sb, 16); sb += __shfl_xor(sb, 32);
    const float ia = 1.0f / fmaxf(sqrtf(sa), 1e-12f);
    const float ib = 1.0f / fmaxf(sqrtf(sb), 1e-12f);

    // ---- normalize+pack in-loop (frees va/vb progressively), 10 MFMAs
    f32x4 accS = {0.f, 0.f, 0.f, 0.f};
    #pragma unroll
    for (int kt = 0; kt < 10; ++kt) {
        bf16x8 af = pack8(va[2 * kt], va[2 * kt + 1], ia);
        bf16x8 bf = pack8(vb[2 * kt], vb[2 * kt + 1], ib);
        accS = __builtin_amdgcn_mfma_f32_16x16x32_bf16(af, bf, accS, 0, 0, 0);
    }

    // ---- pool + per-wave reduce, 4 rounds (C row = koct*4+r, col = frow)
    float* pslice = partial + (((size_t)(b * NC + c) * 2 + dt) * Qn + qt * 16) * Kn;
    #pragma unroll
    for (int r = 0; r < 4; ++r) {
        const float s = accS[r];
        #pragma unroll
        for (int k = 0; k < Kn; ++k) {
            const float mu = (k == 0) ? 1.0f : (0.95f - 0.1f * (float)(k - 1));
            const float cf = (k == 0) ? -500000.0f : -50.0f;  // -1/(2*sigma^2)
            const float d = s - mu;
            const float e = __expf(cf * d * d);
            red[w][koct][frow][k] = dvalid ? e : 0.f;
        }
        WAVE_FENCE();
        // 84 outputs (4 koct-rows x 21 k), sum over the 16 frow columns
        #pragma unroll
        for (int i0 = 0; i0 < 2; ++i0) {
            const int i = lane + i0 * 64;
            if (i < 84) {
                const int ko = i / 21, k = i - ko * 21;
                float sum = 0.f;
                #pragma unroll
                for (int f = 0; f < 16; ++f) sum += red[w][ko][f][k];
                pslice[(ko * 4 + r) * Kn + k] = sum;
            }
        }
        WAVE_FENCE();   // reads done before next round overwrites red
    }
}

__global__ __launch_bounds__(704)
void knrm_reduce(const int* __restrict__ qlen_arr, const int* __restrict__ dlen_arr,
                 const float* __restrict__ partial, const float* __restrict__ dense_w,
                 const float* __restrict__ dense_b, float* __restrict__ out)
{
    __shared__ float sq[Qn * Kn];
    __shared__ float lk[Kn];
    const int b = blockIdx.x;
    const int t = threadIdx.x;
    const int qlen = qlen_arr[b];
    const int ncu = min((dlen_arr[b] + 31) >> 5, NC);   // only written slices
    if (t < Qn * Kn) {
        const int q = t / Kn, k = t - q * Kn;
        float s = 0.f;
        for (int c = 0; c < ncu; ++c) {
            s += partial[((((size_t)b * NC + c) * 2 + 0) * Qn + q) * Kn + k];
            s += partial[((((size_t)b * NC + c) * 2 + 1) * Qn + q) * Kn + k];
        }
        sq[t] = (q < qlen) ? 0.01f * logf(fmaxf(s, 1e-10f)) : 0.f;
    }
    __syncthreads();
    if (t < Kn) {
        float l = 0.f;
        #pragma unroll
        for (int q = 0; q < Qn; ++q) l += sq[q * Kn + t];
        out[Bn + (size_t)b * Kn + t] = l;   // log_pooling_sum (B,K)
        lk[t] = l;
    }
    __syncthreads();
    if (t == 0) {
        float sc = dense_b[0];
        #pragma unroll
        for (int k = 0; k < Kn; ++k) sc += lk[k] * dense_w[k];
        out[b] = sc;                        // score (B,)
    }
}

extern "C" void kernel_launch(void* const* d_in, const int* in_sizes, int n_in,
                              void* d_out, int out_size, void* d_ws, size_t ws_size,
                              hipStream_t stream)
{
    const int*   qidx  = (const int*)d_in[0];
    const int*   didx  = (const int*)d_in[1];
    const int*   qlen  = (const int*)d_in[2];
    const int*   dlen  = (const int*)d_in[3];
    const float* table = (const float*)d_in[4];
    const float* dw    = (const float*)d_in[5];
    const float* db    = (const float*)d_in[6];
    float* out = (float*)d_out;
    float* partial = (float*)d_ws;   // 128*16*2*32*21 floats = 11 MB << ws (256 MiB);
                                     // only slices with c < ceil(dlen/32) are read.

    knrm_main<<<dim3(Bn * NC), dim3(NTHR), 0, stream>>>(qidx, didx, dlen, table, partial);
    knrm_reduce<<<dim3(Bn), dim3(704), 0, stream>>>(qlen, dlen, partial, dw, db, out);
}

// Round 7
// 26.790 us; speedup vs baseline: 1.6245x; 1.6245x over previous
//
#include <hip/hip_runtime.h>

#define Bn 128
#define Qn 32
#define Dn 512
#define En 300
#define Kn 21
#define CH 32                  // docs per chunk
#define JBLK 4                 // blocks per batch
#define MAXIT 4                // chunks per block (strided by JBLK)
#define NKT 10                 // k-tiles of 32 (covers 320 >= 300, zero-padded)
#define LDE 40                 // shorts per row within one k-tile (80 B)
#define TILE_SH (CH * LDE)     // 1280 shorts per k-tile
#define SIMLD 36               // sim row stride (floats): 144 B, 16B-aligned
#define NTHR 256

typedef __attribute__((ext_vector_type(8))) short bf16x8;
typedef __attribute__((ext_vector_type(4))) float f32x4;

// LDS map (bytes):
//   dbuf [0, 25600)        short[NKT][CH][LDE]
//   qbuf [25600, 51200)    same; dead after af-hoist -> sim float[32][SIMLD] (4608 B) aliases it
//   idx  [51200, 51840)    int[JBLK*CH? no: MAXIT*CH=128 doc tokens + 32 q tokens]
#define SMEM_BYTES 51840       // -> 3 blocks/CU (155.5 KB of 160)

__device__ __forceinline__ float dot4(float4 a, float4 b) {
    return a.x * b.x + a.y * b.y + a.z * b.z + a.w * b.w;
}

__global__ __launch_bounds__(NTHR, 3)
void knrm_main(const int* __restrict__ qidx, const int* __restrict__ didx,
               const int* __restrict__ dlen_arr, const float* __restrict__ table,
               float* __restrict__ partial)
{
    // XCD-contiguous remap (512 % 8 == 0, bijective): a batch's 4 blocks share an XCD L2
    const int g = blockIdx.x;
    const int idx2 = (g & 7) * 64 + (g >> 3);
    const int b = idx2 >> 2;
    const int j = idx2 & 3;
    const int dlen = dlen_arr[b];
    float* pbase = partial + (size_t)(b * JBLK + j) * Qn * Kn;

    const int t = threadIdx.x;
    int nc = 0;
    #pragma unroll
    for (int i = 0; i < MAXIT; ++i) if ((j + JBLK * i) * CH < dlen) nc = i + 1;
    if (nc == 0) {               // zero partial (ws is poisoned); reduce sums all 4 j
        for (int i = t; i < Qn * Kn; i += NTHR) pbase[i] = 0.f;
        return;
    }

    __shared__ __align__(16) char smem[SMEM_BYTES];
    short* dbuf = (short*)smem;
    short* qbuf = (short*)(smem + 25600);
    float* sim  = (float*)(smem + 25600);     // alias: live only after af-hoist
    int*   idxd = (int*)(smem + 51200);       // [MAXIT][CH]
    int*   idxq = idxd + MAXIT * CH;          // [Qn]

    // ---- stage tokens (-1 sentinel -> zero rows)
    if (t < MAXIT * CH) {
        const int i = t >> 5, r = t & 31;
        const int doc = (j + JBLK * i) * CH + r;
        idxd[t] = (doc < dlen) ? didx[b * Dn + doc] : -1;
    } else if (t < MAXIT * CH + Qn) {
        idxq[t - MAXIT * CH] = qidx[b * Qn + (t - MAXIT * CH)];
    }
    __syncthreads();

    const int row = t >> 3;      // 32 rows / 256 thr: one row per 8-lane octet
    const int il  = t & 7;

    float4 ld[NKT];
    auto issue = [&](int tok) {                       // 10 independent gathers
        #pragma unroll
        for (int j2 = 0; j2 < NKT; ++j2) {
            const int k = j2 * 32 + il * 4;
            float4 v = {0.f, 0.f, 0.f, 0.f};
            if (k <= 296 && tok >= 0) v = *(const float4*)(table + (size_t)tok * En + k);
            ld[j2] = v;
        }
    };
    auto commit = [&](short* dst) {                   // octet row-norm + bf16 pack
        float ss = 0.f;
        #pragma unroll
        for (int j2 = 0; j2 < NKT; ++j2) ss += dot4(ld[j2], ld[j2]);
        ss += __shfl_xor(ss, 1);
        ss += __shfl_xor(ss, 2);
        ss += __shfl_xor(ss, 4);
        const float inv = 1.0f / fmaxf(sqrtf(ss), 1e-12f);
        #pragma unroll
        for (int j2 = 0; j2 < NKT; ++j2) {
            const unsigned ax = __float_as_uint(ld[j2].x * inv) + 0x8000u;
            const unsigned ay = __float_as_uint(ld[j2].y * inv) + 0x8000u;
            const unsigned az = __float_as_uint(ld[j2].z * inv) + 0x8000u;
            const unsigned aw = __float_as_uint(ld[j2].w * inv) + 0x8000u;
            uint2 p;
            p.x = __builtin_amdgcn_perm(ay, ax, 0x07060302u);
            p.y = __builtin_amdgcn_perm(aw, az, 0x07060302u);
            *(uint2*)&dst[j2 * TILE_SH + row * LDE + il * 4] = p;
        }
    };

    const int lane = t & 63;
    const int w = t >> 6;        // wave -> (qt, dt) quadrant of the 32x32 sim tile
    const int qt = w >> 1;
    const int dt = w & 1;
    const int frow = lane & 15;
    const int koct = lane >> 4;

    // ---- prologue
    issue(idxq[row]);
    commit(qbuf);
    issue(idxd[row]);            // chunk 0, in flight across the barrier
    __syncthreads();

    bf16x8 af[NKT];              // hoist loop-invariant q fragments; qbuf dead after
    #pragma unroll
    for (int kt = 0; kt < NKT; ++kt)
        af[kt] = *(const bf16x8*)&qbuf[kt * TILE_SH + (qt * 16 + frow) * LDE + koct * 8];
    commit(dbuf);
    __syncthreads();

    // ---- pooling ownership: thread = (q row, k-triple)
    const int pq = t >> 3;
    const int kg = t & 7;        // kg<7: k = kg*3 + {0,1,2}; kg==7 idle in pool
    float mu[3], cf[3];
    #pragma unroll
    for (int kk = 0; kk < 3; ++kk) {
        const int k = kg * 3 + kk;
        mu[kk] = (k == 0) ? 1.0f : 1.05f - 0.1f * (float)k;
        cf[kk] = (k == 0) ? -500000.0f : -50.0f;      // -1/(2*sigma^2)
    }
    float acc[3] = {0.f, 0.f, 0.f};

    for (int it = 0; it < nc; ++it) {
        const bool more = (it + 1 < nc);
        if (more) issue(idxd[(it + 1) * CH + row]);   // prefetch next chunk

        f32x4 accS = {0.f, 0.f, 0.f, 0.f};
        #pragma unroll
        for (int kt = 0; kt < NKT; ++kt) {
            bf16x8 bf = *(const bf16x8*)&dbuf[kt * TILE_SH + (dt * 16 + frow) * LDE + koct * 8];
            accS = __builtin_amdgcn_mfma_f32_16x16x32_bf16(af[kt], bf, accS, 0, 0, 0);
        }
        // C layout: col=frow (doc), row=koct*4+r (q within tile)
        #pragma unroll
        for (int r = 0; r < 4; ++r)
            sim[(qt * 16 + koct * 4 + r) * SIMLD + dt * 16 + frow] = accS[r];
        __syncthreads();

        if (more) commit(dbuf);                       // next chunk -> dbuf (MFMA reads done)

        if (kg < 7) {
            const int cbase = (j + JBLK * it) * CH;
            #pragma unroll
            for (int f4 = 0; f4 < 8; ++f4) {
                const float4 sv = *(const float4*)&sim[pq * SIMLD + f4 * 4];
                #pragma unroll
                for (int e = 0; e < 4; ++e) {
                    const float se = (e == 0) ? sv.x : (e == 1) ? sv.y : (e == 2) ? sv.z : sv.w;
                    const float s = (cbase + f4 * 4 + e < dlen) ? se : 1.0e3f;  // masked -> exp 0
                    #pragma unroll
                    for (int kk = 0; kk < 3; ++kk) {
                        const float d = s - mu[kk];
                        acc[kk] += __expf(cf[kk] * d * d);
                    }
                }
            }
        }
        __syncthreads();         // sim reads done; dbuf visible for next MFMA
    }

    // ---- epilogue: 3 direct stores per pooling thread (no reduction needed)
    if (kg < 7) {
        #pragma unroll
        for (int kk = 0; kk < 3; ++kk)
            pbase[pq * Kn + kg * 3 + kk] = acc[kk];
    }
}

__global__ __launch_bounds__(704)
void knrm_reduce(const int* __restrict__ qlen_arr, const float* __restrict__ partial,
                 const float* __restrict__ dense_w, const float* __restrict__ dense_b,
                 float* __restrict__ out)
{
    __shared__ float sq[Qn * Kn];
    __shared__ float lk[Kn];
    const int b = blockIdx.x;
    const int t = threadIdx.x;
    const int qlen = qlen_arr[b];
    if (t < Qn * Kn) {
        const int q = t / Kn, k = t - q * Kn;
        float s = 0.f;
        #pragma unroll
        for (int c = 0; c < JBLK; ++c)
            s += partial[(((size_t)b * JBLK + c) * Qn + q) * Kn + k];
        sq[t] = (q < qlen) ? 0.01f * logf(fmaxf(s, 1e-10f)) : 0.f;
    }
    __syncthreads();
    if (t < Kn) {
        float l = 0.f;
        #pragma unroll
        for (int q = 0; q < Qn; ++q) l += sq[q * Kn + t];
        out[Bn + (size_t)b * Kn + t] = l;   // log_pooling_sum (B,K)
        lk[t] = l;
    }
    __syncthreads();
    if (t == 0) {
        float sc = dense_b[0];
        #pragma unroll
        for (int k = 0; k < Kn; ++k) sc += lk[k] * dense_w[k];
        out[b] = sc;                        // score (B,)
    }
}

extern "C" void kernel_launch(void* const* d_in, const int* in_sizes, int n_in,
                              void* d_out, int out_size, void* d_ws, size_t ws_size,
                              hipStream_t stream)
{
    const int*   qidx  = (const int*)d_in[0];
    const int*   didx  = (const int*)d_in[1];
    const int*   qlen  = (const int*)d_in[2];
    const int*   dlen  = (const int*)d_in[3];
    const float* table = (const float*)d_in[4];
    const float* dw    = (const float*)d_in[5];
    const float* db    = (const float*)d_in[6];
    float* out = (float*)d_out;
    float* partial = (float*)d_ws;   // B*JBLK*Qn*Kn floats = 1.38 MB, fully overwritten

    knrm_main<<<dim3(Bn * JBLK), dim3(NTHR), 0, stream>>>(qidx, didx, dlen, table, partial);
    knrm_reduce<<<dim3(Bn), dim3(704), 0, stream>>>(qlen, partial, dw, db, out);
}